// Round 9
// baseline (116.093 us; speedup 1.0000x reference)
//
#include <hip/hip_runtime.h>

#define BATCH  2048
#define TLEN   128
#define CH     5
#define SIGDIM 780               // 5 + 25 + 125 + 625
#define KACC   16                // global accumulator copies
#define PPB    4                 // paths per block (4 waves; wave w = path w, halves = time segs)
#define NBLK   ((2 * BATCH) / PPB)   // 1024
#define SEGR   64                // steps per segment (seg1: 63 real + 1 zero pad)

// Wave w = path (pbase+w); half h (lanes h*32..) = time-segment h (64 steps).
// Lane u<25 owns chain ab=u: s1a, s2, s3[5], s4[25] in regs.
// In-loop DS traffic is broadcast-only: 1x b128 (d0..d3) per step + 1x b128
// (four steps' d4) per 4 steps; da/db are cndmask selects from registers
// (multi-address DS gathers were the measured bottleneck, ~6cyc/distinct addr).
// After the loop: half 1 publishes its segment sig to LDS; half 0 Chen-combines
// (L in registers, R from LDS) into blockAcc; last block reduces ||u-v||^2/B^2.
__global__ __launch_bounds__(256, 4) void sig_kernel(
    const float* __restrict__ x, const float* __restrict__ y,
    const float* __restrict__ sigma, float* __restrict__ acc,
    unsigned int* __restrict__ counter, float* __restrict__ out) {
  const int tid  = threadIdx.x;
  const int wave = tid >> 6;
  const int lane = tid & 63;
  const int h    = lane >> 5;          // time segment
  const int u    = lane & 31;          // sublane within half
  const bool isX = (blockIdx.x < NBLK / 2);
  const int pbase = (isX ? blockIdx.x : blockIdx.x - NBLK / 2) * PPB;
  const int path  = pbase + wave;
  const float* src = (isX ? x : y) + (size_t)path * (TLEN * CH) + h * (SEGR * CH);

  __shared__ __align__(16) float main4[2 * PPB][SEGR * 4]; // [seg][t*4+c], c<4 (8 KB)
  __shared__ __align__(16) float aux4 [2 * PPB][SEGR];     // [seg][t] = d4   (2 KB)
  __shared__ float sigbuf[PPB][SIGDIM];                    // seg-1 signatures (12.5 KB)
  __shared__ float blockAcc[SIGDIM];
  __shared__ float red[4];
  __shared__ unsigned int lastFlag;

  for (int i = tid; i < SIGDIM; i += 256) blockAcc[i] = 0.f;

  // sigma -> registers once (uniform scalar loads)
  const float sg0 = sigma[0], sg1 = sigma[1], sg2 = sigma[2], sg3 = sigma[3];

  // ---- fill increments; seg1 has 63 real rows + zero row 63 ----
  const int seg = wave * 2 + h;
  float* mw = main4[seg];
  float* aw = aux4[seg];
  if (h == 1) {
    if (u < 4) mw[63 * 4 + u] = 0.f;
    if (u == 4) aw[63] = 0.f;
  }
  const int lim = h ? 63 * CH : 64 * CH;
  for (int i = u; i < lim; i += 32) {
    int t = i / CH, c = i - CH * t;
    float v = src[i + CH] - src[i];
    if (isX && c > 0) {
      const float s = (c == 1) ? sg0 : (c == 2) ? sg1 : (c == 3) ? sg2 : sg3;
      v *= s;
    }
    if (c < 4) mw[t * 4 + c] = v; else aw[t] = v;
  }
  __syncthreads();

  // ---- ownership (loop-invariant masks for register selects) ----
  const int  uc = u < 25 ? u : 24;     // clamp idle sublanes 25..31
  const int  a_ = uc / 5, b_ = uc - 5 * a_;
  const bool fa0 = (a_ == 0), fa1 = (a_ == 1), fa2 = (a_ == 2), fa3 = (a_ == 3);
  const bool fb0 = (b_ == 0), fb1 = (b_ == 1), fb2 = (b_ == 2), fb3 = (b_ == 3);
  const bool act = (u < 25);

  float s1a = 0.f, s2 = 0.f;
  float s3[5] = {0,0,0,0,0};
  float s4[5][5] = {{0,0,0,0,0},{0,0,0,0,0},{0,0,0,0,0},{0,0,0,0,0},{0,0,0,0,0}};

  // ---- main loop: 16 groups x 4 steps; DS = 5x b128 per group, broadcast ----
  for (int g = 0; g < 16; ++g) {
    const float4 e = *(const float4*)(aw + g * 4);   // d4 of steps 4g..4g+3
    const float* mg = mw + g * 16;
    #pragma unroll
    for (int k = 0; k < 4; ++k) {
      const float4 m = *(const float4*)(mg + k * 4);
      const float d0 = m.x, d1 = m.y, d2 = m.z, d3 = m.w;
      const float d4 = (k == 0) ? e.x : (k == 1) ? e.y : (k == 2) ? e.z : e.w;
      const float da = fa0 ? d0 : fa1 ? d1 : fa2 ? d2 : fa3 ? d3 : d4;
      const float db = fb0 ? d0 : fb1 ? d1 : fb2 ? d2 : fb3 ? d3 : d4;
      // level-1 helpers (old s1a)
      const float pa = s1a * (1.f / 6.f) + da * (1.f / 24.f);
      const float qa = s1a * 0.5f        + da * (1.f / 6.f);
      const float rr = s1a               + da * 0.5f;
      s1a += da;
      // level-2 (old s2)
      const float p2 = 0.5f * s2 + db * pa;
      const float q2 =        s2 + db * qa;
      s2 += db * rr;
      // level-3/4: all 5 prefixes of this chain
      #pragma unroll
      for (int c = 0; c < 5; ++c) {
        const float dc = c == 0 ? d0 : c == 1 ? d1 : c == 2 ? d2 : c == 3 ? d3 : d4;
        const float p3 = s3[c] + dc * p2;
        s3[c] += dc * q2;
        s4[c][0] += d0 * p3; s4[c][1] += d1 * p3; s4[c][2] += d2 * p3;
        s4[c][3] += d3 * p3; s4[c][4] += d4 * p3;
      }
    }
  }

  // ---- half 1 publishes its segment signature ----
  if (h == 1 && act) {
    float* sgb = sigbuf[wave];
    if (b_ == 0) sgb[a_] = s1a;
    sgb[5 + uc] = s2;
    #pragma unroll
    for (int c = 0; c < 5; ++c) {
      sgb[30 + uc * 5 + c] = s3[c];
      #pragma unroll
      for (int d = 0; d < 5; ++d) sgb[155 + (uc * 5 + c) * 5 + d] = s4[c][d];
    }
  }
  __syncthreads();

  // ---- half 0: Chen combine S = SL (x) SR, L in regs, R = sigbuf[wave] ----
  if (h == 0 && act) {
    const float* R = sigbuf[wave];
    const float o1 = s1a + R[a_];
    const float o2 = s2 + s1a * R[b_] + R[5 + uc];
    if (b_ == 0) atomicAdd(&blockAcc[a_], o1);
    atomicAdd(&blockAcc[5 + uc], o2);
    #pragma unroll
    for (int c = 0; c < 5; ++c) {
      const float o3 = s3[c] + s2 * R[c] + s1a * R[5 + b_ * 5 + c] + R[30 + uc * 5 + c];
      atomicAdd(&blockAcc[30 + uc * 5 + c], o3);
      #pragma unroll
      for (int d = 0; d < 5; ++d) {
        const float o4 = s4[c][d] + s3[c] * R[d] + s2 * R[5 + c * 5 + d]
                       + s1a * R[30 + (b_ * 5 + c) * 5 + d]
                       + R[155 + (uc * 5 + c) * 5 + d];
        atomicAdd(&blockAcc[155 + (uc * 5 + c) * 5 + d], o4);
      }
    }
  }
  __syncthreads();

  // ---- signed block -> global ----
  const float w = isX ? 1.0f : -1.0f;
  float* ap = acc + (size_t)(blockIdx.x & (KACC - 1)) * SIGDIM;
  for (int i = tid; i < SIGDIM; i += 256)
    atomicAdd(ap + i, w * blockAcc[i]);

  // ---- fused final reduction: last block computes ||u-v||^2 / B^2 ----
  __syncthreads();
  if (tid == 0) {
    __threadfence();
    unsigned int old = __hip_atomic_fetch_add(counter, 1u, __ATOMIC_ACQ_REL,
                                              __HIP_MEMORY_SCOPE_AGENT);
    lastFlag = (old == NBLK - 1) ? 1u : 0u;
  }
  __syncthreads();
  if (lastFlag) {
    float local = 0.f;
    for (int i = tid; i < SIGDIM; i += 256) {
      float v = 0.f;
      #pragma unroll
      for (int k = 0; k < KACC; ++k)
        v += __hip_atomic_load(&acc[(size_t)k * SIGDIM + i],
                               __ATOMIC_RELAXED, __HIP_MEMORY_SCOPE_AGENT);
      local += v * v;
    }
    #pragma unroll
    for (int off = 32; off > 0; off >>= 1) local += __shfl_down(local, off, 64);
    if ((tid & 63) == 0) red[tid >> 6] = local;
    __syncthreads();
    if (tid == 0)
      out[0] = (red[0] + red[1] + red[2] + red[3]) / (2048.0f * 2048.0f);
  }
}

extern "C" void kernel_launch(void* const* d_in, const int* in_sizes, int n_in,
                              void* d_out, int out_size, void* d_ws, size_t ws_size,
                              hipStream_t stream) {
  const float* x     = (const float*)d_in[0];
  const float* y     = (const float*)d_in[1];
  const float* sigma = (const float*)d_in[2];
  float* out = (float*)d_out;
  float* acc = (float*)d_ws;
  unsigned int* counter = (unsigned int*)((char*)d_ws + (size_t)KACC * SIGDIM * sizeof(float));

  hipMemsetAsync(d_ws, 0, (size_t)KACC * SIGDIM * sizeof(float) + 64, stream);
  sig_kernel<<<dim3(NBLK), dim3(256), 0, stream>>>(x, y, sigma, acc, counter, out);
}

// Round 10
// 108.985 us; speedup vs baseline: 1.0652x; 1.0652x over previous
//
#include <hip/hip_runtime.h>

typedef float v2f __attribute__((ext_vector_type(2)));

#define BATCH  2048
#define TLEN   128
#define CH     5
#define SIGDIM 780               // 5 + 25 + 125 + 625
#define KACC   16                // global accumulator copies
#define PPB    4                 // paths per block (wave w = path w; halves = time segs)
#define NBLK   ((2 * BATCH) / PPB)   // 1024
#define SEGR   64                // steps per segment (seg1: 63 real + 1 zero pad)

// R8 structure (best measured: 57.5us) + packed-fp32 level-3/4 (v_pk_fma_f32).
// Wave w = path (pbase+w); half h (lanes h*32..) = time-segment h (64 steps).
// Lane u<25 owns chain ab=u: s1a, s2, s3 (2x v2f + 1), s4 (10x v2f + 5) in regs.
// Selects da/db are DS gathers (measured faster than cndmask chains, R8 vs R9).
// After loop: half 1 publishes segment sig to LDS; half 0 Chen-combines
// (L in regs, R from LDS) into blockAcc; last block reduces ||u-v||^2/B^2.
__global__ __launch_bounds__(256, 4) void sig_kernel(
    const float* __restrict__ x, const float* __restrict__ y,
    const float* __restrict__ sigma, float* __restrict__ acc,
    unsigned int* __restrict__ counter, float* __restrict__ out) {
  const int tid  = threadIdx.x;
  const int wave = tid >> 6;
  const int lane = tid & 63;
  const int h    = lane >> 5;          // time segment
  const int u    = lane & 31;          // sublane within half
  const bool isX = (blockIdx.x < NBLK / 2);
  const int pbase = (isX ? blockIdx.x : blockIdx.x - NBLK / 2) * PPB;
  const int path  = pbase + wave;
  const float* src = (isX ? x : y) + (size_t)path * (TLEN * CH) + h * (SEGR * CH);

  __shared__ __align__(16) float buf[2 * PPB][784];  // [seg]: increments rows t*8; then seg-1 sig
  __shared__ float blockAcc[SIGDIM];
  __shared__ float red[4];
  __shared__ unsigned int lastFlag;

  for (int i = tid; i < SIGDIM; i += 256) blockAcc[i] = 0.f;

  // sigma -> registers once
  const float sg0 = sigma[0], sg1 = sigma[1], sg2 = sigma[2], sg3 = sigma[3];

  // ---- fill increments; seg1 has 63 real rows + zero row 63 ----
  float* bw = buf[wave * 2 + h];
  if (h == 1 && u < 8) bw[63 * 8 + u] = 0.f;
  const int lim = h ? 63 * CH : 64 * CH;
  for (int i = u; i < lim; i += 32) {
    int t = i / CH, c = i - CH * t;
    float v = src[i + CH] - src[i];
    if (isX && c > 0) {
      const float s = (c == 1) ? sg0 : (c == 2) ? sg1 : (c == 3) ? sg2 : sg3;
      v *= s;
    }
    bw[t * 8 + c] = v;
  }
  __syncthreads();

  // ---- ownership ----
  const int  uc = u < 25 ? u : 24;     // clamp idle sublanes 25..31
  const int  a_ = uc / 5, b_ = uc - 5 * a_;
  const bool act = (u < 25);

  float s1a = 0.f, s2 = 0.f;
  v2f   s3p0 = {0.f, 0.f}, s3p1 = {0.f, 0.f};
  float s3e = 0.f;
  v2f   s4p0[5] = {{0,0},{0,0},{0,0},{0,0},{0,0}};   // c in {0,1}
  v2f   s4p1[5] = {{0,0},{0,0},{0,0},{0,0},{0,0}};   // c in {2,3}
  float s4e[5]  = {0,0,0,0,0};                       // c == 4

  const float* pa_ = bw + a_;          // per-lane da gather stream
  const float* pb_ = bw + b_;          // per-lane db gather stream

  // ---- main loop: 8 groups x 8 steps (seg1 row 63 = zero no-op) ----
  for (int g = 0; g < 8; ++g) {
    const float* rg = bw + g * 64;
    const float* ra = pa_ + g * 64;
    const float* rb = pb_ + g * 64;
    #pragma unroll
    for (int k = 0; k < 8; ++k) {
      const float4 m = *(const float4*)(rg + k * 8);
      const float d0 = m.x, d1 = m.y, d2 = m.z, d3 = m.w;
      const float d4 = rg[k * 8 + 4];
      const float da = ra[k * 8];
      const float db = rb[k * 8];
      // level-1 helpers (old s1a)
      const float pa = s1a * (1.f / 6.f) + da * (1.f / 24.f);
      const float qa = s1a * 0.5f        + da * (1.f / 6.f);
      const float rr = s1a               + da * 0.5f;
      s1a += da;
      // level-2 (old s2)
      const float p2 = 0.5f * s2 + db * pa;
      const float q2 =        s2 + db * qa;
      s2 += db * rr;
      // level-3/4, packed over c: pairs (d0,d1), (d2,d3), scalar d4
      const v2f dc01 = {d0, d1};
      const v2f dc23 = {d2, d3};
      const v2f p2v  = {p2, p2};
      const v2f q2v  = {q2, q2};
      const v2f p30  = __builtin_elementwise_fma(dc01, p2v, s3p0);
      const v2f p31  = __builtin_elementwise_fma(dc23, p2v, s3p1);
      const float p3e = s3e + d4 * p2;
      s3p0 = __builtin_elementwise_fma(dc01, q2v, s3p0);
      s3p1 = __builtin_elementwise_fma(dc23, q2v, s3p1);
      s3e += d4 * q2;
      #pragma unroll
      for (int d = 0; d < 5; ++d) {
        const float dd = (d == 0) ? d0 : (d == 1) ? d1 : (d == 2) ? d2 : (d == 3) ? d3 : d4;
        const v2f ddv = {dd, dd};
        s4p0[d] = __builtin_elementwise_fma(ddv, p30, s4p0[d]);
        s4p1[d] = __builtin_elementwise_fma(ddv, p31, s4p1[d]);
        s4e[d] += dd * p3e;
      }
    }
  }

  // unpack packed state for epilogue
  float S3[5] = {s3p0.x, s3p0.y, s3p1.x, s3p1.y, s3e};
  float S4[5][5];
  #pragma unroll
  for (int d = 0; d < 5; ++d) {
    S4[0][d] = s4p0[d].x; S4[1][d] = s4p0[d].y;
    S4[2][d] = s4p1[d].x; S4[3][d] = s4p1[d].y;
    S4[4][d] = s4e[d];
  }

  // ---- half 1 publishes its segment signature (increments are dead) ----
  if (h == 1 && act) {
    float* sgb = bw;
    if (b_ == 0) sgb[a_] = s1a;
    sgb[5 + uc] = s2;
    #pragma unroll
    for (int c = 0; c < 5; ++c) {
      sgb[30 + uc * 5 + c] = S3[c];
      #pragma unroll
      for (int d = 0; d < 5; ++d) sgb[155 + (uc * 5 + c) * 5 + d] = S4[c][d];
    }
  }
  __syncthreads();

  // ---- half 0: Chen combine S = SL (x) SR, L in regs, R = buf[wave*2+1] ----
  if (h == 0 && act) {
    const float* R = buf[wave * 2 + 1];
    const float o1 = s1a + R[a_];
    const float o2 = s2 + s1a * R[b_] + R[5 + uc];
    if (b_ == 0) atomicAdd(&blockAcc[a_], o1);
    atomicAdd(&blockAcc[5 + uc], o2);
    #pragma unroll
    for (int c = 0; c < 5; ++c) {
      const float o3 = S3[c] + s2 * R[c] + s1a * R[5 + b_ * 5 + c] + R[30 + uc * 5 + c];
      atomicAdd(&blockAcc[30 + uc * 5 + c], o3);
      #pragma unroll
      for (int d = 0; d < 5; ++d) {
        const float o4 = S4[c][d] + S3[c] * R[d] + s2 * R[5 + c * 5 + d]
                       + s1a * R[30 + (b_ * 5 + c) * 5 + d]
                       + R[155 + (uc * 5 + c) * 5 + d];
        atomicAdd(&blockAcc[155 + (uc * 5 + c) * 5 + d], o4);
      }
    }
  }
  __syncthreads();

  // ---- signed block -> global ----
  const float w = isX ? 1.0f : -1.0f;
  float* ap = acc + (size_t)(blockIdx.x & (KACC - 1)) * SIGDIM;
  for (int i = tid; i < SIGDIM; i += 256)
    atomicAdd(ap + i, w * blockAcc[i]);

  // ---- fused final reduction: last block computes ||u-v||^2 / B^2 ----
  __syncthreads();
  if (tid == 0) {
    __threadfence();
    unsigned int old = __hip_atomic_fetch_add(counter, 1u, __ATOMIC_ACQ_REL,
                                              __HIP_MEMORY_SCOPE_AGENT);
    lastFlag = (old == NBLK - 1) ? 1u : 0u;
  }
  __syncthreads();
  if (lastFlag) {
    float local = 0.f;
    for (int i = tid; i < SIGDIM; i += 256) {
      float v = 0.f;
      #pragma unroll
      for (int k = 0; k < KACC; ++k)
        v += __hip_atomic_load(&acc[(size_t)k * SIGDIM + i],
                               __ATOMIC_RELAXED, __HIP_MEMORY_SCOPE_AGENT);
      local += v * v;
    }
    #pragma unroll
    for (int off = 32; off > 0; off >>= 1) local += __shfl_down(local, off, 64);
    if ((tid & 63) == 0) red[tid >> 6] = local;
    __syncthreads();
    if (tid == 0)
      out[0] = (red[0] + red[1] + red[2] + red[3]) / (2048.0f * 2048.0f);
  }
}

extern "C" void kernel_launch(void* const* d_in, const int* in_sizes, int n_in,
                              void* d_out, int out_size, void* d_ws, size_t ws_size,
                              hipStream_t stream) {
  const float* x     = (const float*)d_in[0];
  const float* y     = (const float*)d_in[1];
  const float* sigma = (const float*)d_in[2];
  float* out = (float*)d_out;
  float* acc = (float*)d_ws;
  unsigned int* counter = (unsigned int*)((char*)d_ws + (size_t)KACC * SIGDIM * sizeof(float));

  hipMemsetAsync(d_ws, 0, (size_t)KACC * SIGDIM * sizeof(float) + 64, stream);
  sig_kernel<<<dim3(NBLK), dim3(256), 0, stream>>>(x, y, sigma, acc, counter, out);
}